// Round 8
// baseline (129.379 us; speedup 1.0000x reference)
//
#include <hip/hip_runtime.h>

// YOLO loss forward, MI355X — round 8.
// R7 post-mortem: main kernel is BW-bound (~6 TB/s total-bytes vs ~6.3 ceil;
// same dur at 15% and 25% occupancy). Remaining slack = the 2nd reduce
// dispatch (~4-6us of wall). This round fuses it: last-block-done pattern
// (partial + release fence + ONE counter atomic per block; 3136 atomics over
// ~30us = 9.5ns spacing, under the ~5.6ns coherence service rate that killed
// R5's 6272 output atomics). Fixed-order reduce in the last block keeps it
// bitwise deterministic. Counter zeroed per replay by in-graph memsetAsync.

#define TPB 256
#define NBLK 3136                     // 802816 / 256, exact

#define GP(x) ((const __attribute__((address_space(1))) void*)(x))
#define LP(x) ((__attribute__((address_space(3))) void*)(x))

__device__ __forceinline__ float iou_f(float a0, float a1, float a2, float a3,
                                       float b0, float b1, float b2, float b3) {
    float ax1 = a0 - a2 * 0.5f, ax2 = a0 + a2 * 0.5f;
    float ay1 = a1 - a3 * 0.5f, ay2 = a1 + a3 * 0.5f;
    float bx1 = b0 - b2 * 0.5f, bx2 = b0 + b2 * 0.5f;
    float by1 = b1 - b3 * 0.5f, by2 = b1 + b3 * 0.5f;
    float iw = fmaxf(fminf(ax2, bx2) - fmaxf(ax1, bx1), 0.0f);
    float ih = fmaxf(fminf(ay2, by2) - fmaxf(ay1, by1), 0.0f);
    float inter = iw * ih;
    float aa = fabsf(a2 * a3);
    float ab = fabsf(b2 * b3);
    return inter / (aa + ab - inter + 1e-6f);
}

__global__ __launch_bounds__(TPB, 2) void yolo_fused(
    const float* __restrict__ pred, const float* __restrict__ targ,
    float* __restrict__ part, unsigned int* __restrict__ counter,
    float* __restrict__ out) {
    __shared__ __align__(16) float sp[TPB * 30];   // 30720 B
    __shared__ __align__(16) float st[TPB * 25];   // 25600 B
    __shared__ float swr[4];
    __shared__ int amLast;

    const int tid = threadIdx.x;
    const int w = tid >> 6;
    const int l = tid & 63;

    // ---- stage this block's 256 cells, fully coalesced, identity LDS layout
    const char* ps = (const char*)pred + (size_t)blockIdx.x * (TPB * 120); // 30720 B
    const char* ts = (const char*)targ + (size_t)blockIdx.x * (TPB * 100); // 25600 B

#pragma unroll
    for (int j = 0; j < 7; ++j)        // 7 * 4096 = 28672 B of pred (w16)
        __builtin_amdgcn_global_load_lds(GP(ps + j * 4096 + w * 1024 + l * 16),
                                         LP((char*)sp + j * 4096 + w * 1024), 16, 0, 0);
#pragma unroll
    for (int j = 0; j < 2; ++j)        // last 2048 B of pred (w4)
        __builtin_amdgcn_global_load_lds(GP(ps + 28672 + j * 1024 + w * 256 + l * 4),
                                         LP((char*)sp + 28672 + j * 1024 + w * 256), 4, 0, 0);
#pragma unroll
    for (int j = 0; j < 6; ++j)        // 6 * 4096 = 24576 B of targ (w16)
        __builtin_amdgcn_global_load_lds(GP(ts + j * 4096 + w * 1024 + l * 16),
                                         LP((char*)st + j * 4096 + w * 1024), 16, 0, 0);
    __builtin_amdgcn_global_load_lds(GP(ts + 24576 + w * 256 + l * 4),
                                     LP((char*)st + 24576 + w * 256), 4, 0, 0); // 1024 B (w4)

    asm volatile("s_waitcnt vmcnt(0)" ::: "memory");
    __syncthreads();

    // ---- per-cell loss from LDS
    const float2* p2 = (const float2*)(sp + tid * 30);  // 8B-aligned (30 even)
    float pv[30];
#pragma unroll
    for (int j = 0; j < 15; ++j) {
        float2 v = p2[j];
        pv[2 * j]     = v.x;
        pv[2 * j + 1] = v.y;
    }
    const float* T = st + tid * 25;
    float tv[25];
#pragma unroll
    for (int j = 0; j < 25; ++j) tv[j] = T[j];

    float cls = 0.0f;
#pragma unroll
    for (int j = 0; j < 20; ++j) {
        float d = pv[j] - tv[j];
        cls += d * d;
    }

    float t0 = tv[20], t1 = tv[21], t2 = tv[22], t3 = tv[23], t4v = tv[24];
    bool obj = (t0 == 1.0f);

    float i1 = iou_f(pv[20], pv[21], pv[22], pv[23], t0, t1, t2, t3);
    float i2 = iou_f(pv[25], pv[26], pv[27], pv[28], t0, t1, t2, t3);
    bool use1 = i1 > i2;

    float r0 = use1 ? pv[20] : pv[25];
    float r1 = use1 ? pv[21] : pv[26];
    float r2 = use1 ? pv[22] : pv[27];
    float r3 = use1 ? pv[23] : pv[28];
    float r4 = use1 ? pv[24] : pv[29];
    float oc = use1 ? pv[29] : pv[24];

    float dx = r0 - t0;
    float dy = r1 - t1;
    float dw = sqrtf(fmaxf(r2, 1e-6f)) - sqrtf(fmaxf(t2, 1e-6f));
    float dh = sqrtf(fmaxf(r3, 1e-6f)) - sqrtf(fmaxf(t3, 1e-6f));
    float coord = 5.0f * (dx * dx + dy * dy + dw * dw + dh * dh);

    float dconf = r4 - t4v;
    float obj_conf = dconf * dconf;

    float noobj_in = 0.5f * oc * oc;
    float noobj_out = 0.5f * (pv[24] * pv[24] + pv[29] * pv[29]);

    float lsum = obj ? (coord + obj_conf + cls + noobj_in) : noobj_out;

    // ---- block reduction (fixed order -> deterministic)
#pragma unroll
    for (int off = 32; off > 0; off >>= 1) lsum += __shfl_down(lsum, off, 64);
    if (l == 0) swr[w] = lsum;
    __syncthreads();

    // ---- publish partial + last-block-done detection
    if (tid == 0) {
        part[blockIdx.x] = swr[0] + swr[1] + swr[2] + swr[3];
        __threadfence();                           // release: partial visible
        unsigned int prev = atomicAdd(counter, 1u);
        amLast = (prev == NBLK - 1u) ? 1 : 0;
    }
    __syncthreads();

    // ---- last block reduces all partials in fixed order (deterministic)
    if (amLast) {
        __threadfence();                           // acquire
        float s = 0.0f;
        for (int i = tid; i < NBLK; i += TPB) s += part[i];
#pragma unroll
        for (int off = 32; off > 0; off >>= 1) s += __shfl_down(s, off, 64);
        if (l == 0) swr[w] = s;
        __syncthreads();
        if (tid == 0)
            out[0] = (swr[0] + swr[1] + swr[2] + swr[3]) * (1.0f / 16384.0f);
    }
}

extern "C" void kernel_launch(void* const* d_in, const int* in_sizes, int n_in,
                              void* d_out, int out_size, void* d_ws, size_t ws_size,
                              hipStream_t stream) {
    const float* pred = (const float*)d_in[0];
    const float* targ = (const float*)d_in[1];
    float* part = (float*)d_ws;                        // 3136 floats
    unsigned int* counter = (unsigned int*)((char*)d_ws + NBLK * sizeof(float));
    float* out = (float*)d_out;

    hipMemsetAsync(counter, 0, sizeof(unsigned int), stream);  // re-zero each replay
    yolo_fused<<<NBLK, TPB, 0, stream>>>(pred, targ, part, counter, out);
}

// Round 9
// 58.123 us; speedup vs baseline: 2.2260x; 2.2260x over previous
//
#include <hip/hip_runtime.h>

// YOLO loss forward, MI355X — round 9.
// R8 post-mortem: per-block __threadfence() (agent-scope release) cost ~60ns
// x 3136 serialized = +135us — fences, not atomics, were the killer. R5 vs R8
// isolated the atomic-rate law: 6272 atomics @4.7ns spacing queue (+35us);
// 3136 @9.4ns hide under execution. This round: R4's proven BW-bound main
// kernel (TPB=256, coalesced global_load_lds staging, ~6.0 TB/s = 95% of the
// 6.29 TB/s ceiling) + ONE relaxed atomicAdd per block directly on d_out
// (pre-scaled, no fence, no partials, no 2nd kernel), in-graph 4B memset.

#define TPB 256
#define NBLK 3136                     // 802816 / 256, exact

#define GP(x) ((const __attribute__((address_space(1))) void*)(x))
#define LP(x) ((__attribute__((address_space(3))) void*)(x))

__device__ __forceinline__ float iou_f(float a0, float a1, float a2, float a3,
                                       float b0, float b1, float b2, float b3) {
    float ax1 = a0 - a2 * 0.5f, ax2 = a0 + a2 * 0.5f;
    float ay1 = a1 - a3 * 0.5f, ay2 = a1 + a3 * 0.5f;
    float bx1 = b0 - b2 * 0.5f, bx2 = b0 + b2 * 0.5f;
    float by1 = b1 - b3 * 0.5f, by2 = b1 + b3 * 0.5f;
    float iw = fmaxf(fminf(ax2, bx2) - fmaxf(ax1, bx1), 0.0f);
    float ih = fmaxf(fminf(ay2, by2) - fmaxf(ay1, by1), 0.0f);
    float inter = iw * ih;
    float aa = fabsf(a2 * a3);
    float ab = fabsf(b2 * b3);
    return inter / (aa + ab - inter + 1e-6f);
}

__global__ __launch_bounds__(TPB, 2) void yolo_cell(
    const float* __restrict__ pred, const float* __restrict__ targ,
    float* __restrict__ out) {
    __shared__ __align__(16) float sp[TPB * 30];   // 30720 B
    __shared__ __align__(16) float st[TPB * 25];   // 25600 B
    __shared__ float swr[4];

    const int tid = threadIdx.x;
    const int w = tid >> 6;
    const int l = tid & 63;

    // ---- stage this block's 256 cells, fully coalesced, identity LDS layout
    const char* ps = (const char*)pred + (size_t)blockIdx.x * (TPB * 120); // 30720 B
    const char* ts = (const char*)targ + (size_t)blockIdx.x * (TPB * 100); // 25600 B

#pragma unroll
    for (int j = 0; j < 7; ++j)        // 7 * 4096 = 28672 B of pred (w16)
        __builtin_amdgcn_global_load_lds(GP(ps + j * 4096 + w * 1024 + l * 16),
                                         LP((char*)sp + j * 4096 + w * 1024), 16, 0, 0);
#pragma unroll
    for (int j = 0; j < 2; ++j)        // last 2048 B of pred (w4)
        __builtin_amdgcn_global_load_lds(GP(ps + 28672 + j * 1024 + w * 256 + l * 4),
                                         LP((char*)sp + 28672 + j * 1024 + w * 256), 4, 0, 0);
#pragma unroll
    for (int j = 0; j < 6; ++j)        // 6 * 4096 = 24576 B of targ (w16)
        __builtin_amdgcn_global_load_lds(GP(ts + j * 4096 + w * 1024 + l * 16),
                                         LP((char*)st + j * 4096 + w * 1024), 16, 0, 0);
    __builtin_amdgcn_global_load_lds(GP(ts + 24576 + w * 256 + l * 4),
                                     LP((char*)st + 24576 + w * 256), 4, 0, 0); // 1024 B (w4)

    asm volatile("s_waitcnt vmcnt(0)" ::: "memory");
    __syncthreads();

    // ---- per-cell loss from LDS
    const float2* p2 = (const float2*)(sp + tid * 30);  // 8B-aligned (30 even)
    float pv[30];
#pragma unroll
    for (int j = 0; j < 15; ++j) {
        float2 v = p2[j];
        pv[2 * j]     = v.x;
        pv[2 * j + 1] = v.y;
    }
    const float* T = st + tid * 25;
    float tv[25];
#pragma unroll
    for (int j = 0; j < 25; ++j) tv[j] = T[j];

    float cls = 0.0f;
#pragma unroll
    for (int j = 0; j < 20; ++j) {
        float d = pv[j] - tv[j];
        cls += d * d;
    }

    float t0 = tv[20], t1 = tv[21], t2 = tv[22], t3 = tv[23], t4v = tv[24];
    bool obj = (t0 == 1.0f);

    float i1 = iou_f(pv[20], pv[21], pv[22], pv[23], t0, t1, t2, t3);
    float i2 = iou_f(pv[25], pv[26], pv[27], pv[28], t0, t1, t2, t3);
    bool use1 = i1 > i2;

    float r0 = use1 ? pv[20] : pv[25];
    float r1 = use1 ? pv[21] : pv[26];
    float r2 = use1 ? pv[22] : pv[27];
    float r3 = use1 ? pv[23] : pv[28];
    float r4 = use1 ? pv[24] : pv[29];
    float oc = use1 ? pv[29] : pv[24];

    float dx = r0 - t0;
    float dy = r1 - t1;
    float dw = sqrtf(fmaxf(r2, 1e-6f)) - sqrtf(fmaxf(t2, 1e-6f));
    float dh = sqrtf(fmaxf(r3, 1e-6f)) - sqrtf(fmaxf(t3, 1e-6f));
    float coord = 5.0f * (dx * dx + dy * dy + dw * dw + dh * dh);

    float dconf = r4 - t4v;
    float obj_conf = dconf * dconf;

    float noobj_in = 0.5f * oc * oc;
    float noobj_out = 0.5f * (pv[24] * pv[24] + pv[29] * pv[29]);

    float lsum = obj ? (coord + obj_conf + cls + noobj_in) : noobj_out;

    // ---- block reduction (fixed order) + one relaxed atomic per block
#pragma unroll
    for (int off = 32; off > 0; off >>= 1) lsum += __shfl_down(lsum, off, 64);
    if (l == 0) swr[w] = lsum;
    __syncthreads();
    if (tid == 0)
        atomicAdd(out, (swr[0] + swr[1] + swr[2] + swr[3]) * (1.0f / 16384.0f));
}

extern "C" void kernel_launch(void* const* d_in, const int* in_sizes, int n_in,
                              void* d_out, int out_size, void* d_ws, size_t ws_size,
                              hipStream_t stream) {
    const float* pred = (const float*)d_in[0];
    const float* targ = (const float*)d_in[1];
    float* out = (float*)d_out;

    hipMemsetAsync(out, 0, sizeof(float), stream);   // re-zero each graph replay
    yolo_cell<<<NBLK, TPB, 0, stream>>>(pred, targ, out);
}

// Round 10
// 32.726 us; speedup vs baseline: 3.9534x; 1.7760x over previous
//
#include <hip/hip_runtime.h>

// YOLO loss forward, MI355X — round 10 (revert to R4 best + lean reduce).
// Atomic-fusion law (R5/R8/R9 A/B): same-line device-scope f32 atomicAdd
// serializes at ~10-16ns/op at the cross-XCD coherence point, and blocks
// can't retire until their atomic drains -> +23..+35us wall. __threadfence
// per block is worse (+135us, L1/L2 writeback storms). Two-kernel
// deterministic reduction is structurally optimal for the tail.
// Main kernel (R4): TPB=256, 256-cell tiles, coalesced global_load_lds
// identity staging, 56.3KB LDS -> 2 blocks/CU, 3136 streaming blocks.
// Delivered ~6.0 TB/s total-bytes = 95% of the 6.29 TB/s achievable ceiling,
// invariant across TPB=64/128/256 (occupancy 15-25%) -> BW-bound.

#define TPB 256
#define NBLK 3136                     // 802816 / 256, exact
constexpr int NPART = NBLK;           // 3136 = 784 float4

#define GP(x) ((const __attribute__((address_space(1))) void*)(x))
#define LP(x) ((__attribute__((address_space(3))) void*)(x))

__device__ __forceinline__ float iou_f(float a0, float a1, float a2, float a3,
                                       float b0, float b1, float b2, float b3) {
    float ax1 = a0 - a2 * 0.5f, ax2 = a0 + a2 * 0.5f;
    float ay1 = a1 - a3 * 0.5f, ay2 = a1 + a3 * 0.5f;
    float bx1 = b0 - b2 * 0.5f, bx2 = b0 + b2 * 0.5f;
    float by1 = b1 - b3 * 0.5f, by2 = b1 + b3 * 0.5f;
    float iw = fmaxf(fminf(ax2, bx2) - fmaxf(ax1, bx1), 0.0f);
    float ih = fmaxf(fminf(ay2, by2) - fmaxf(ay1, by1), 0.0f);
    float inter = iw * ih;
    float aa = fabsf(a2 * a3);
    float ab = fabsf(b2 * b3);
    return inter / (aa + ab - inter + 1e-6f);
}

__global__ __launch_bounds__(TPB, 2) void yolo_cell(
    const float* __restrict__ pred, const float* __restrict__ targ,
    float* __restrict__ part) {
    __shared__ __align__(16) float sp[TPB * 30];   // 30720 B
    __shared__ __align__(16) float st[TPB * 25];   // 25600 B
    __shared__ float swr[4];

    const int tid = threadIdx.x;
    const int w = tid >> 6;
    const int l = tid & 63;

    // ---- stage this block's 256 cells, fully coalesced, identity LDS layout
    const char* ps = (const char*)pred + (size_t)blockIdx.x * (TPB * 120); // 30720 B
    const char* ts = (const char*)targ + (size_t)blockIdx.x * (TPB * 100); // 25600 B

#pragma unroll
    for (int j = 0; j < 7; ++j)        // 7 * 4096 = 28672 B of pred (w16)
        __builtin_amdgcn_global_load_lds(GP(ps + j * 4096 + w * 1024 + l * 16),
                                         LP((char*)sp + j * 4096 + w * 1024), 16, 0, 0);
#pragma unroll
    for (int j = 0; j < 2; ++j)        // last 2048 B of pred (w4)
        __builtin_amdgcn_global_load_lds(GP(ps + 28672 + j * 1024 + w * 256 + l * 4),
                                         LP((char*)sp + 28672 + j * 1024 + w * 256), 4, 0, 0);
#pragma unroll
    for (int j = 0; j < 6; ++j)        // 6 * 4096 = 24576 B of targ (w16)
        __builtin_amdgcn_global_load_lds(GP(ts + j * 4096 + w * 1024 + l * 16),
                                         LP((char*)st + j * 4096 + w * 1024), 16, 0, 0);
    __builtin_amdgcn_global_load_lds(GP(ts + 24576 + w * 256 + l * 4),
                                     LP((char*)st + 24576 + w * 256), 4, 0, 0); // 1024 B (w4)

    asm volatile("s_waitcnt vmcnt(0)" ::: "memory");
    __syncthreads();

    // ---- per-cell loss from LDS
    const float2* p2 = (const float2*)(sp + tid * 30);  // 8B-aligned (30 even)
    float pv[30];
#pragma unroll
    for (int j = 0; j < 15; ++j) {
        float2 v = p2[j];
        pv[2 * j]     = v.x;
        pv[2 * j + 1] = v.y;
    }
    const float* T = st + tid * 25;
    float tv[25];
#pragma unroll
    for (int j = 0; j < 25; ++j) tv[j] = T[j];

    float cls = 0.0f;
#pragma unroll
    for (int j = 0; j < 20; ++j) {
        float d = pv[j] - tv[j];
        cls += d * d;
    }

    float t0 = tv[20], t1 = tv[21], t2 = tv[22], t3 = tv[23], t4v = tv[24];
    bool obj = (t0 == 1.0f);

    float i1 = iou_f(pv[20], pv[21], pv[22], pv[23], t0, t1, t2, t3);
    float i2 = iou_f(pv[25], pv[26], pv[27], pv[28], t0, t1, t2, t3);
    bool use1 = i1 > i2;

    float r0 = use1 ? pv[20] : pv[25];
    float r1 = use1 ? pv[21] : pv[26];
    float r2 = use1 ? pv[22] : pv[27];
    float r3 = use1 ? pv[23] : pv[28];
    float r4 = use1 ? pv[24] : pv[29];
    float oc = use1 ? pv[29] : pv[24];

    float dx = r0 - t0;
    float dy = r1 - t1;
    float dw = sqrtf(fmaxf(r2, 1e-6f)) - sqrtf(fmaxf(t2, 1e-6f));
    float dh = sqrtf(fmaxf(r3, 1e-6f)) - sqrtf(fmaxf(t3, 1e-6f));
    float coord = 5.0f * (dx * dx + dy * dy + dw * dw + dh * dh);

    float dconf = r4 - t4v;
    float obj_conf = dconf * dconf;

    float noobj_in = 0.5f * oc * oc;
    float noobj_out = 0.5f * (pv[24] * pv[24] + pv[29] * pv[29]);

    float lsum = obj ? (coord + obj_conf + cls + noobj_in) : noobj_out;

    // ---- block reduction (fixed order -> deterministic)
#pragma unroll
    for (int off = 32; off > 0; off >>= 1) lsum += __shfl_down(lsum, off, 64);
    if (l == 0) swr[w] = lsum;
    __syncthreads();
    if (tid == 0) part[blockIdx.x] = swr[0] + swr[1] + swr[2] + swr[3];
}

__global__ __launch_bounds__(256) void yolo_reduce(const float* __restrict__ part,
                                                   float* __restrict__ out) {
    __shared__ float swr[4];
    const int tid = threadIdx.x;
    const float4* p4 = (const float4*)part;          // 784 float4s
    float s = 0.0f;
    for (int i = tid; i < NPART / 4; i += 256) {     // 4 iters (last partial)
        float4 v = p4[i];
        s += (v.x + v.y) + (v.z + v.w);
    }
#pragma unroll
    for (int off = 32; off > 0; off >>= 1) s += __shfl_down(s, off, 64);
    if ((tid & 63) == 0) swr[tid >> 6] = s;
    __syncthreads();
    if (tid == 0) out[0] = (swr[0] + swr[1] + swr[2] + swr[3]) * (1.0f / 16384.0f);
}

extern "C" void kernel_launch(void* const* d_in, const int* in_sizes, int n_in,
                              void* d_out, int out_size, void* d_ws, size_t ws_size,
                              hipStream_t stream) {
    const float* pred = (const float*)d_in[0];
    const float* targ = (const float*)d_in[1];
    float* part = (float*)d_ws;   // 3136 floats = 12.5 KB (16B-aligned ws)
    float* out = (float*)d_out;

    yolo_cell<<<NBLK, TPB, 0, stream>>>(pred, targ, part);
    yolo_reduce<<<1, 256, 0, stream>>>(part, out);
}